// Round 1
// baseline (661.254 us; speedup 1.0000x reference)
//
#include <hip/hip_runtime.h>
#include <stdint.h>

#define NN 128
#define BB 4096
#define HH 32

typedef float f4 __attribute__((ext_vector_type(4)));

// Pre-pass: bit-pack A transposed. bit d of word (b,node) = (A[b][d][node] != 0).
// float4-vectorized: each thread owns 4 consecutive nodes, walks all 128 rows d.
// 16 B/lane loads (coalescing sweet spot), nontemporal (A = 268 MB, read once).
__global__ __launch_bounds__(256) void pack_bits(const float* __restrict__ A,
                                                 ulonglong2* __restrict__ bitsT) {
    const int tid = blockIdx.x * 256 + threadIdx.x;   // BB*32 threads total
    const int b   = tid >> 5;
    const int ng  = (tid & 31) << 2;                  // this thread's 4 nodes
    const float* Ab = A + (size_t)b * (NN * NN) + ng;
    unsigned long long w0[4] = {0ull, 0ull, 0ull, 0ull};
    unsigned long long w1[4] = {0ull, 0ull, 0ull, 0ull};
#pragma unroll 8
    for (int d = 0; d < 64; ++d) {
        f4 v = __builtin_nontemporal_load((const f4*)(Ab + (size_t)d * NN));
        const unsigned long long bit = 1ull << d;
        if (v[0] != 0.f) w0[0] |= bit;
        if (v[1] != 0.f) w0[1] |= bit;
        if (v[2] != 0.f) w0[2] |= bit;
        if (v[3] != 0.f) w0[3] |= bit;
    }
#pragma unroll 8
    for (int d = 0; d < 64; ++d) {
        f4 v = __builtin_nontemporal_load((const f4*)(Ab + (size_t)(d + 64) * NN));
        const unsigned long long bit = 1ull << d;
        if (v[0] != 0.f) w1[0] |= bit;
        if (v[1] != 0.f) w1[1] |= bit;
        if (v[2] != 0.f) w1[2] |= bit;
        if (v[3] != 0.f) w1[3] |= bit;
    }
    ulonglong2* o = bitsT + b * NN + ng;
#pragma unroll
    for (int i = 0; i < 4; ++i) {
        ulonglong2 r; r.x = w0[i]; r.y = w1[i];
        o[i] = r;
    }
}

// One wave (64 lanes) per batch element. outputs state: out0 (d=lane), out1 (d=lane+64).
// v2: no __syncthreads (single wave -> wave-local lgkmcnt-only sync keeps the
// vmcnt-tracked prefetches alive across the step); order/bits/x/b2 live in
// registers and are broadcast via shfl; W2/b1/W1-xrow rows pipelined one step
// ahead; p-reduction via DPP instead of 5 ds-shuffle hops.
__global__ __launch_bounds__(64) void cond_mlp(
    const float* __restrict__ x, const float* __restrict__ u,
    const float* __restrict__ W1, const float* __restrict__ b1,
    const float* __restrict__ W2, const float* __restrict__ b2,
    const int* __restrict__ order, const int* __restrict__ do_idxs,
    const ulonglong2* __restrict__ bitsT, float* __restrict__ out)
{
    const int b = blockIdx.x;
    const int lane = threadIdx.x;
    const int j = lane & 31;       // hidden index
    const int half = lane >> 5;    // which k-stream pair this lane serves

    __shared__ float2 ent[132];    // compacted (value, rowbyteoff/4) list

    const float ub = u[b];
    const int dob = do_idxs[b];
    float out0 = (dob == lane) ? ub : 0.f;
    float out1 = (dob == lane + 64) ? ub : 0.f;

    // ---- preload all per-b uniform data into registers (coalesced, once) ----
    const int* ord = order + b * NN;
    const int orA = ord[lane];
    const int orB = ord[lane + 64];
    const ulonglong2 B0 = bitsT[(size_t)b * NN + lane];        // bits of node `lane`
    const ulonglong2 B1 = bitsT[(size_t)b * NN + 64 + lane];   // bits of node `lane+64`
    const float xr0 = x[b * NN + lane];
    const float xr1 = x[b * NN + 64 + lane];
    const float b2r0 = b2[lane];
    const float b2r1 = b2[lane + 64];

    const unsigned long long lanebit = 1ull << lane;
    const unsigned long long below = lanebit - 1ull;

    // ---- prologue: node for t=0 ----
    int node = __builtin_amdgcn_readfirstlane(__shfl(orA, 0));
    unsigned long long bitsx = __shfl((node & 64) ? B1.x : B0.x, node & 63);
    unsigned long long bitsy = __shfl((node & 64) ? B1.y : B0.y, node & 63);
    const float* Wn = W1 + (size_t)node * ((NN + 1) * HH);
    float w2v  = W2[node * HH + j];
    float b1v  = b1[node * HH + j];
    float w1xv = Wn[NN * HH + j];          // W1 row 128 (the x input row)

    for (int t = 0; t < NN; ++t) {
        // ---- prefetch next step (stays in flight: no vmcnt(0) drains) ----
        const int nsel = (t + 1) & 127;
        const int node_n = __builtin_amdgcn_readfirstlane(
            __shfl((nsel & 64) ? orB : orA, nsel & 63));
        const unsigned long long bx_n = __shfl((node_n & 64) ? B1.x : B0.x, node_n & 63);
        const unsigned long long by_n = __shfl((node_n & 64) ? B1.y : B0.y, node_n & 63);
        const float* Wn_n = W1 + (size_t)node_n * ((NN + 1) * HH);
        const float w2v_n  = W2[node_n * HH + j];
        const float b1v_n  = b1[node_n * HH + j];
        const float w1xv_n = Wn_n[NN * HH + j];

        // current-node scalars straight from registers (no memory)
        const float xv  = __shfl((node & 64) ? xr1 : xr0, node & 63);
        const float b2v = __shfl((node & 64) ? b2r1 : b2r0, node & 63);

        // ---- wave-uniform sparse compaction ----
        unsigned long long bal0 = __ballot(out0 != 0.f) & bitsx;
        unsigned long long bal1 = __ballot(out1 != 0.f) & bitsy;
        const int c0 = __popcll(bal0);
        const int cnt = c0 + __popcll(bal1);
        if (bal0 & lanebit) {
            int p = __popcll(bal0 & below);
            ent[p] = make_float2(out0, __int_as_float(lane << 5));      // d*HH pre-shifted
        }
        if (bal1 & lanebit) {
            int p = c0 + __popcll(bal1 & below);
            ent[p] = make_float2(out1, __int_as_float((lane + 64) << 5));
        }
        const int cnt4 = (cnt + 3) & ~3;
        if (lane < cnt4 - cnt) ent[cnt + lane] = make_float2(0.f, __int_as_float(0));
        // single wave: only LDS visibility needed, don't drain vmcnt
        asm volatile("s_waitcnt lgkmcnt(0)" ::: "memory");

        // ---- sparse gather: half 0 takes k, k+2; half 1 takes k+1, k+3 ----
        float acc0 = 0.f, acc1 = 0.f;
        for (int k = 0; k < cnt4; k += 4) {
            float2 eA = ent[k + half];
            float2 eB = ent[k + 2 + half];
            int dA = __float_as_int(eA.y);
            int dB = __float_as_int(eB.y);
            acc0 += eA.x * Wn[dA + j];
            acc1 += eB.x * Wn[dB + j];
        }
        // no second barrier needed: DS ops are in-order per wave and all ent
        // reads are consumed (via acc) before next iteration's writes issue.

        float acc = acc0 + acc1;
        acc += __shfl_xor(acc, 32);            // merge the two k-stream pairs
        acc += xv * w1xv;                      // the x input row (row 128)
        acc += b1v;
        const float hv = (acc > 0.f) ? acc : 0.01f * acc;   // leaky_relu

        // H -> 1 reduction over the 32 j-lanes: 4 DPP hops + one xor16
        float p = hv * w2v;
        p += __int_as_float(__builtin_amdgcn_update_dpp(
                 0, __float_as_int(p), 0xB1, 0xF, 0xF, true));   // quad_perm xor1
        p += __int_as_float(__builtin_amdgcn_update_dpp(
                 0, __float_as_int(p), 0x4E, 0xF, 0xF, true));   // quad_perm xor2
        p += __int_as_float(__builtin_amdgcn_update_dpp(
                 0, __float_as_int(p), 0x141, 0xF, 0xF, true));  // row_half_mirror (xor4)
        p += __int_as_float(__builtin_amdgcn_update_dpp(
                 0, __float_as_int(p), 0x140, 0xF, 0xF, true));  // row_mirror (xor8)
        p += __shfl_xor(p, 16);
        const float outv = p + b2v;

        // ---- state update (skip if this is the do-intervention node) ----
        if (dob != node && lane == (node & 63)) {
            if (node < 64) out0 = outv; else out1 = outv;
        }

        node = node_n; bitsx = bx_n; bitsy = by_n;
        Wn = Wn_n; w2v = w2v_n; b1v = b1v_n; w1xv = w1xv_n;
    }

    out[b * NN + lane] = out0;
    out[b * NN + 64 + lane] = out1;
}

extern "C" void kernel_launch(void* const* d_in, const int* in_sizes, int n_in,
                              void* d_out, int out_size, void* d_ws, size_t ws_size,
                              hipStream_t stream) {
    const float* x   = (const float*)d_in[0];
    const float* A   = (const float*)d_in[1];
    const float* u   = (const float*)d_in[2];
    const float* W1  = (const float*)d_in[3];
    const float* b1  = (const float*)d_in[4];
    const float* W2  = (const float*)d_in[5];
    const float* b2  = (const float*)d_in[6];
    const int* order = (const int*)d_in[7];
    const int* dox   = (const int*)d_in[8];

    ulonglong2* bitsT = (ulonglong2*)d_ws;  // needs 4096*128*16 B = 8 MB

    pack_bits<<<(BB * 32) / 256, 256, 0, stream>>>(A, bitsT);
    cond_mlp<<<BB, 64, 0, stream>>>(x, u, W1, b1, W2, b2, order, dox,
                                    bitsT, (float*)d_out);
}

// Round 2
// 545.128 us; speedup vs baseline: 1.2130x; 1.2130x over previous
//
#include <hip/hip_runtime.h>
#include <stdint.h>

#define NN 128
#define BB 4096
#define HH 32

typedef float f4 __attribute__((ext_vector_type(4)));

// Pre-pass: bit-pack A transposed. bit d of word (b,node) = (A[b][d][node] != 0).
// float4-vectorized: each thread owns 4 consecutive nodes, walks all 128 rows d.
__global__ __launch_bounds__(256) void pack_bits(const float* __restrict__ A,
                                                 ulonglong2* __restrict__ bitsT) {
    const int tid = blockIdx.x * 256 + threadIdx.x;   // BB*32 threads total
    const int b   = tid >> 5;
    const int ng  = (tid & 31) << 2;                  // this thread's 4 nodes
    const float* Ab = A + (size_t)b * (NN * NN) + ng;
    unsigned long long w0[4] = {0ull, 0ull, 0ull, 0ull};
    unsigned long long w1[4] = {0ull, 0ull, 0ull, 0ull};
#pragma unroll 8
    for (int d = 0; d < 64; ++d) {
        f4 v = __builtin_nontemporal_load((const f4*)(Ab + (size_t)d * NN));
        const unsigned long long bit = 1ull << d;
        if (v[0] != 0.f) w0[0] |= bit;
        if (v[1] != 0.f) w0[1] |= bit;
        if (v[2] != 0.f) w0[2] |= bit;
        if (v[3] != 0.f) w0[3] |= bit;
    }
#pragma unroll 8
    for (int d = 0; d < 64; ++d) {
        f4 v = __builtin_nontemporal_load((const f4*)(Ab + (size_t)(d + 64) * NN));
        const unsigned long long bit = 1ull << d;
        if (v[0] != 0.f) w1[0] |= bit;
        if (v[1] != 0.f) w1[1] |= bit;
        if (v[2] != 0.f) w1[2] |= bit;
        if (v[3] != 0.f) w1[3] |= bit;
    }
    ulonglong2* o = bitsT + b * NN + ng;
#pragma unroll
    for (int i = 0; i < 4; ++i) {
        ulonglong2 r; r.x = w0[i]; r.y = w1[i];
        o[i] = r;
    }
}

// One wave (64 lanes) per batch element. outputs state: out0 (d=lane), out1 (d=lane+64).
// v3 = v0 structure (memory-prefetch pipeline) with ONLY the barrier fix:
//   - __syncthreads (s_waitcnt vmcnt(0) lgkmcnt(0) + s_barrier) drained the
//     one-step-ahead bitsT prefetch + epilogue loads every step. Single-wave
//     block needs only lgkmcnt(0) for LDS write->read visibility.
//   - trailing barrier removed: same-wave DS ops execute in program order,
//     so next step's ent writes cannot bypass this step's ent reads
//     (validated: round-1 kernel with this scheme passed the harness check).
//   - reduction hops xor1/2/4/8 via DPP (VALU) instead of ds-shuffles.
__global__ __launch_bounds__(64) void cond_mlp(
    const float* __restrict__ x, const float* __restrict__ u,
    const float* __restrict__ W1, const float* __restrict__ b1,
    const float* __restrict__ W2, const float* __restrict__ b2,
    const int* __restrict__ order, const int* __restrict__ do_idxs,
    const ulonglong2* __restrict__ bitsT, float* __restrict__ out)
{
    const int b = blockIdx.x;
    const int lane = threadIdx.x;
    const int j = lane & 31;       // hidden index
    const int half = lane >> 5;    // which k-stream this lane serves

    __shared__ float2 ent[132];    // compacted (value, d*HH as int) list

    const float ub = u[b];
    const int dob = do_idxs[b];
    float out0 = (dob == lane) ? ub : 0.f;
    float out1 = (dob == lane + 64) ? ub : 0.f;

    const int* ord = order + b * NN;
    const ulonglong2* bb = bitsT + (size_t)b * NN;

    const unsigned long long lanebit = 1ull << lane;
    const unsigned long long below = lanebit - 1ull;

    int node = ord[0];
    ulonglong2 bits = bb[node];

    for (int t = 0; t < NN; ++t) {
        // ---- prefetch next step's uniform data (now stays in flight:
        //      no vmcnt(0) drain anywhere in the loop) ----
        const int node_n = (t < NN - 1) ? ord[t + 1] : 0;
        const ulonglong2 bits_n = bb[node_n];

        const float* Wn = W1 + (size_t)node * (NN + 1) * HH;
        // issue epilogue loads early (consumed after the gather loop)
        const float w2v  = W2[node * HH + j];
        const float b1v  = b1[node * HH + j];
        const float xv   = x[b * NN + node];
        const float b2v  = b2[node];
        const float w1xv = Wn[NN * HH + j];   // W1 row 128 (the x input row)

        // ---- wave-uniform sparse compaction ----
        unsigned long long bal0 = __ballot(out0 != 0.f) & bits.x;
        unsigned long long bal1 = __ballot(out1 != 0.f) & bits.y;
        const int c0 = __popcll(bal0);
        const int cnt = c0 + __popcll(bal1);
        if (bal0 & lanebit) {
            int p = __popcll(bal0 & below);
            ent[p] = make_float2(out0, __int_as_float(lane << 5));       // d*HH pre-shifted
        }
        if (bal1 & lanebit) {
            int p = c0 + __popcll(bal1 & below);
            ent[p] = make_float2(out1, __int_as_float((lane + 64) << 5));
        }
        const int cnt4 = (cnt + 3) & ~3;
        if (lane < cnt4 - cnt) ent[cnt + lane] = make_float2(0.f, __int_as_float(0));
        // single wave: LDS visibility only — do NOT drain vmcnt
        asm volatile("s_waitcnt lgkmcnt(0)" ::: "memory");

        // ---- sparse gather: half 0 takes k, k+2; half 1 takes k+1, k+3 ----
        float acc0 = 0.f, acc1 = 0.f;
        for (int k = 0; k < cnt4; k += 4) {
            float2 eA = ent[k + half];
            float2 eB = ent[k + 2 + half];
            acc0 += eA.x * Wn[__float_as_int(eA.y) + j];
            acc1 += eB.x * Wn[__float_as_int(eB.y) + j];
        }
        // (no trailing barrier — see header comment)

        float acc = acc0 + acc1;
        acc += __shfl_xor(acc, 32);            // merge the two k-streams
        acc += xv * w1xv;                      // the x input row (row 128)
        acc += b1v;
        const float hv = (acc > 0.f) ? acc : 0.01f * acc;   // leaky_relu

        // H -> 1 reduction over the 32 j-lanes: 4 DPP hops + one xor16.
        // (xor1, xor2, half-mirror(=xor4 after quads equal), mirror(=xor8
        //  after octs equal) — correctness HW-validated in round 1.)
        float p = hv * w2v;
        p += __int_as_float(__builtin_amdgcn_update_dpp(
                 0, __float_as_int(p), 0xB1, 0xF, 0xF, true));   // quad_perm xor1
        p += __int_as_float(__builtin_amdgcn_update_dpp(
                 0, __float_as_int(p), 0x4E, 0xF, 0xF, true));   // quad_perm xor2
        p += __int_as_float(__builtin_amdgcn_update_dpp(
                 0, __float_as_int(p), 0x141, 0xF, 0xF, true));  // row_half_mirror
        p += __int_as_float(__builtin_amdgcn_update_dpp(
                 0, __float_as_int(p), 0x140, 0xF, 0xF, true));  // row_mirror
        p += __shfl_xor(p, 16);
        const float outv = p + b2v;

        // ---- state update (skip if this is the do-intervention node) ----
        if (dob != node && lane == (node & 63)) {
            if (node < 64) out0 = outv; else out1 = outv;
        }
        node = node_n;
        bits = bits_n;
    }

    out[b * NN + lane] = out0;
    out[b * NN + 64 + lane] = out1;
}

extern "C" void kernel_launch(void* const* d_in, const int* in_sizes, int n_in,
                              void* d_out, int out_size, void* d_ws, size_t ws_size,
                              hipStream_t stream) {
    const float* x   = (const float*)d_in[0];
    const float* A   = (const float*)d_in[1];
    const float* u   = (const float*)d_in[2];
    const float* W1  = (const float*)d_in[3];
    const float* b1  = (const float*)d_in[4];
    const float* W2  = (const float*)d_in[5];
    const float* b2  = (const float*)d_in[6];
    const int* order = (const int*)d_in[7];
    const int* dox   = (const int*)d_in[8];

    ulonglong2* bitsT = (ulonglong2*)d_ws;  // needs 4096*128*16 B = 8 MB

    pack_bits<<<(BB * 32) / 256, 256, 0, stream>>>(A, bitsT);
    cond_mlp<<<BB, 64, 0, stream>>>(x, u, W1, b1, W2, b2, order, dox,
                                    bitsT, (float*)d_out);
}